// Round 4
// baseline (286.182 us; speedup 1.0000x reference)
//
#include <hip/hip_runtime.h>
#include <hip/hip_fp16.h>

#define D 64
#define NBMAX 512      // max buckets (nodes/256, N<=131072)
#define BCAP 5120      // per-bucket capacity
#define TILE 64        // nodes per block in tile_layer
#define ASTH 72        // LDS bf16 acc row stride in halves (144B: 16B-aligned, 2-way banks)
#define ACAP 448       // per-wave LDS adjacency buffer (entries)
// R3 result: register accumulation (no LDS atomics / divergent flush) took
// 372.5 -> 277.6 us; tile_layer ~42 us each, fixed (CSR+pool+prescale) ~152 us.
// R4 theory: sweep VGPR ~75+ -> coarse halving (m69: waves halve at vgpr=64)
// puts tile_layer at 4 blocks/CU (16/32 waves) -> latency-hiding-starved.
// Two co-compiled variants, attributed via totals (per-kernel counters are
// blinded by 42us harness reset-fills):
//   tile_layer4 (layer 1): batch-4 sweep, no bounds  -- in-run baseline.
//   tile_layer2 (layers 2,3): batch-2 sweep + __launch_bounds__(256,8)
//     (VGPR<=64 -> 8 blocks/CU = 32 waves; half per-wave MLP, 2x waves).
// Shared trims: bf16 LDS acc with dis premultiplied at write (LDS 24576->16384,
// 8-block capacity), per-cc B-frag epilogue (peak -32 VGPR), 32-bit gather offsets.

typedef __attribute__((ext_vector_type(8))) short short8;
typedef __attribute__((ext_vector_type(4))) float float4v;

static __device__ __forceinline__ unsigned short f2bf(float x) {
    unsigned u = __float_as_uint(x);
    u += 0x7FFFu + ((u >> 16) & 1);   // RNE
    return (unsigned short)(u >> 16);
}

__global__ void zero_ints(int* __restrict__ p, int n) {
    int i = blockIdx.x * blockDim.x + threadIdx.x;
    if (i < n) p[i] = 0;
}

// x (fp32) -> xh (fp16), pre-scaled by dis[row]: s = dis[n]*x[n]
__global__ void prescale_x(const float* __restrict__ x, const float* __restrict__ dis,
                           __half* __restrict__ out, int n2) {
    int i = blockIdx.x * blockDim.x + threadIdx.x;
    if (i < n2) {
        int n = i >> 5;                 // 32 half2 per row
        float d = dis[n];
        float2 v = ((const float2*)x)[i];
        ((__half2*)out)[i] = __floats2half2_rn(v.x * d, v.y * d);
    }
}

// Bin edges into buckets of 256 consecutive dst nodes. Entry packed to 4B:
// (src << 8) | (dst & 255)   (src < 2^24).
__global__ __launch_bounds__(256) void bucket_scatter(const int* __restrict__ src,
                                                      const int* __restrict__ dst, int E,
                                                      int nb, int* __restrict__ gcursor,
                                                      unsigned* __restrict__ bpair) {
    __shared__ int lhist[NBMAX];
    __shared__ int lbase[NBMAX];
    int t = threadIdx.x;
    for (int i = t; i < nb; i += 256) lhist[i] = 0;
    __syncthreads();
    int e0 = blockIdx.x * 4096, e1 = min(e0 + 4096, E);
    for (int e = e0 + t; e < e1; e += 256) atomicAdd(&lhist[dst[e] >> 8], 1);
    __syncthreads();
    for (int i = t; i < nb; i += 256) {
        int c = lhist[i];
        lbase[i] = c ? atomicAdd(&gcursor[i], c) : 0;
        lhist[i] = 0;
    }
    __syncthreads();
    for (int e = e0 + t; e < e1; e += 256) {
        int d = dst[e];
        int b = d >> 8;
        int r = lbase[b] + atomicAdd(&lhist[b], 1);
        if (r < BCAP)
            bpair[(long)b * BCAP + r] = ((unsigned)src[e] << 8) | (unsigned)(d & 255);
    }
}

// Exclusive scan of nb (<512) bucket counts -> gbase, total at gbase[nb].
__global__ void scan_buckets(const int* __restrict__ gcursor, int B, int* __restrict__ gbase) {
    __shared__ int s[512];
    int t = threadIdx.x;
    s[t] = (t < B) ? gcursor[t] : 0;
    __syncthreads();
    for (int off = 1; off < 512; off <<= 1) {
        int v = (t >= off) ? s[t - off] : 0;
        __syncthreads();
        s[t] += v;
        __syncthreads();
    }
    if (t < B) gbase[t] = (t == 0) ? 0 : s[t - 1];
    if (t == 0) gbase[B] = s[511];
}

// One block per bucket: local histogram + scan in LDS, emit row_ptr/dis and
// adj entries packed as (src << 6) | (dst & 63)  (tile-local dst, TILE=64).
__global__ __launch_bounds__(256) void bucket_build(const unsigned* __restrict__ bpair,
                                                    int nb, int N,
                                                    const int* __restrict__ gcursor,
                                                    const int* __restrict__ gbase,
                                                    int* __restrict__ row_ptr,
                                                    float* __restrict__ dis,
                                                    int* __restrict__ adj) {
    __shared__ int hist[256];
    __shared__ int cur[256];
    __shared__ int wsum[4];
    int b = blockIdx.x, t = threadIdx.x;
    int cnt = gcursor[b];
    if (cnt > BCAP) cnt = BCAP;
    int ebase = gbase[b];
    const unsigned* bp = bpair + (long)b * BCAP;

    hist[t] = 0;
    __syncthreads();
    for (int i = t; i < cnt; i += 256) atomicAdd(&hist[bp[i] & 255u], 1);
    __syncthreads();
    int val = hist[t];
    int lane = t & 63, wv = t >> 6;
    int v = val;
#pragma unroll
    for (int off = 1; off < 64; off <<= 1) {
        int u = __shfl_up(v, off, 64);
        if (lane >= off) v += u;
    }
    if (lane == 63) wsum[wv] = v;
    __syncthreads();
    int wo = 0;
#pragma unroll
    for (int w = 0; w < 4; w++)
        if (w < wv) wo += wsum[w];
    int excl = wo + v - val;
    int node = (b << 8) + t;
    if (node < N) {
        row_ptr[node] = ebase + excl;
        dis[node] = rsqrtf((float)(val + 1));  // +1 self-loop
    }
    cur[t] = ebase + excl;
    __syncthreads();
    for (int i = t; i < cnt; i += 256) {
        unsigned p = bp[i];
        unsigned dl = p & 255u;
        int pos = atomicAdd(&cur[dl], 1);
        adj[pos] = (int)((p >> 8) << 6) | (int)(dl & 63u);
    }
    if (b == 0 && t == 0) row_ptr[N] = gbase[nb];
}

// Tile GCN layer body on pre-scaled storage s[n] = dis[n]*h[n]:
//   y[n] = dis[n] * ( sum_a s[a] + s[n] );  o = relu(y @ W + b); store (*dis if scale_out)
// Block = 64-node tile, 4 waves x 16 rows. Lane = (row = lane>>2, c = lane&3):
// each lane OWNS 16 channels (32B) of one node row, walks that row's CSR edge
// list gathering src-row chunks (2 x int4, NB edges in flight) into 16 fp32
// registers. No LDS atomics, no divergence in the hot loop. Epilogue: multiply
// by dis(row), convert bf16, ONE plain LDS write (acc is bf16, MFMA-ready);
// wave-local waitcnt (each wave reads back only rows it owns); per-wave MFMA
// with B-fragments loaded per output-quadrant (cc) to cap register peak.
template <int NB>
static __device__ __forceinline__ void tile_layer_body(const __half* __restrict__ in,
                                                       const int* __restrict__ row_ptr,
                                                       const int* __restrict__ adj,
                                                       const float* __restrict__ dis,
                                                       const float* __restrict__ Wg,
                                                       const float* __restrict__ bias,
                                                       __half* __restrict__ out,
                                                       int N, int scale_out) {
    __shared__ __align__(16) unsigned short accb[TILE * ASTH];  // 9216 B bf16 acc
    __shared__ int adjbuf[4][ACAP];                             // 7168 B wave-private

    int t = threadIdx.x;
    int lane = t & 63;
    int w = t >> 6;
    int row = lane >> 2;                    // wave-local row 0..15
    int c = lane & 3;                       // 16-float channel chunk
    int col = lane & 15, quad = lane >> 4;  // epilogue MFMA coords

    int t0 = blockIdx.x * TILE;
    int wbase = t0 + w * 16;
    int node = wbase + row;

    // per-lane CSR range (empty for tail rows)
    int e0r = 0, e1r = 0;
    if (node < N) { e0r = row_ptr[node]; e1r = row_ptr[node + 1]; }

    const char* inb = (const char*)in;
    int* adjw = adjbuf[w];
    unsigned coff = (unsigned)c * 32u;      // byte offset of chunk within 128B row

    float a[16];
#pragma unroll
    for (int j = 0; j < 16; j++) a[j] = 0.f;

#define ADD16(xa, ya)                                                   \
    {                                                                   \
        const __half2* h0 = (const __half2*)&(xa);                      \
        const __half2* h1 = (const __half2*)&(ya);                      \
        _Pragma("unroll")                                               \
        for (int j = 0; j < 4; j++) {                                   \
            float2 f = __half22float2(h0[j]);                           \
            a[2 * j] += f.x; a[2 * j + 1] += f.y;                       \
        }                                                               \
        _Pragma("unroll")                                               \
        for (int j = 0; j < 4; j++) {                                   \
            float2 f = __half22float2(h1[j]);                           \
            a[8 + 2 * j] += f.x; a[8 + 2 * j + 1] += f.y;               \
        }                                                               \
    }

    if (node < N) {
        unsigned rb = (unsigned)node * 128u + coff;
        int4 xa = *(const int4*)(inb + rb);
        int4 xb = *(const int4*)(inb + rb + 16);
        ADD16(xa, xb)
    }

    // ---- edge sweep: wave's contiguous CSR range, staged in ACAP chunks ----
    int wn0 = min(wbase, N);
    int wn1 = min(wbase + 16, N);
    int eb_w = row_ptr[wn0];
    int ee_w = row_ptr[wn1];

    for (int base = eb_w; base < ee_w; base += ACAP) {
        int clen = min(ACAP, ee_w - base);
        // cooperative wave-copy of adj slice (coalesced dwords); wave-private.
        for (int i = lane; i < clen; i += 64) adjw[i] = adj[base + i];
        __builtin_amdgcn_s_waitcnt(0);   // drain lds writes + vm before reads

        int ls = max(e0r - base, 0);
        int le = min(e1r - base, clen);
        int cnt = max(le - ls, 0);
        int kmax = cnt;
#pragma unroll
        for (int off = 32; off >= 1; off >>= 1) {
            int o = __shfl_xor(kmax, off, 64);
            kmax = max(kmax, o);
        }
        int sidx = min(ls, clen - 1);    // safe clamped index for short lanes

        for (int k = 0; k < kmax; k += NB) {
            bool ok[NB];
            unsigned ro[NB];
            int4 xa[NB], xb[NB];
#pragma unroll
            for (int u = 0; u < NB; u++) {
                int idx = ls + k + u;
                ok[u] = idx < le;
                int pk = adjw[ok[u] ? idx : sidx];
                ro[u] = (unsigned)(pk >> 6) * 128u + coff;
            }
#pragma unroll
            for (int u = 0; u < NB; u++) {
                xa[u] = *(const int4*)(inb + ro[u]);
                xb[u] = *(const int4*)(inb + ro[u] + 16);
            }
#pragma unroll
            for (int u = 0; u < NB; u++)
                if (ok[u]) ADD16(xa[u], xb[u])
        }
    }
#undef ADD16

    // scale by dis(own row), convert to bf16, single plain LDS write (32B)
    float dA = (node < N) ? dis[node] : 0.f;
    unsigned short* ab = &accb[(w * 16 + row) * ASTH + c * 16];
    unsigned pk[8];
#pragma unroll
    for (int j = 0; j < 8; j++)
        pk[j] = (unsigned)f2bf(a[2 * j] * dA) | ((unsigned)f2bf(a[2 * j + 1] * dA) << 16);
    *(int4*)ab = make_int4((int)pk[0], (int)pk[1], (int)pk[2], (int)pk[3]);
    *(int4*)(ab + 8) = make_int4((int)pk[4], (int)pk[5], (int)pk[6], (int)pk[7]);
    __builtin_amdgcn_s_waitcnt(0);   // wave-local: acc rows read only by this wave

    // ---- MFMA epilogue: per wave, rows w*16 .. w*16+15 ----
    // A frags: row m = col, k = 32s + quad*8 + j (bf16 direct from LDS)
    const unsigned short* arp = &accb[(w * 16 + col) * ASTH + quad * 8];
    short8 Af0 = *(const short8*)arp;
    short8 Af1 = *(const short8*)(arp + 32);

    float dnv[4];
#pragma unroll
    for (int r = 0; r < 4; r++) {
        int onode = t0 + w * 16 + quad * 4 + r;
        dnv[r] = (onode < N) ? (scale_out ? dis[onode] : 1.f) : 0.f;
    }

    // B frags per output quadrant cc: B[k=32s+quad*8+j][d=16cc+col]
#pragma unroll
    for (int cc = 0; cc < 4; cc++) {
        short8 B0, B1;
#pragma unroll
        for (int j = 0; j < 8; j++) {
            B0[j] = (short)f2bf(Wg[(quad * 8 + j) * D + 16 * cc + col]);
            B1[j] = (short)f2bf(Wg[(32 + quad * 8 + j) * D + 16 * cc + col]);
        }
        float4v z = {0.f, 0.f, 0.f, 0.f};
        float4v v = __builtin_amdgcn_mfma_f32_16x16x32_bf16(Af0, B0, z, 0, 0, 0);
        v = __builtin_amdgcn_mfma_f32_16x16x32_bf16(Af1, B1, v, 0, 0, 0);
        float bc = bias[16 * cc + col];
        // C layout: col = lane&15 (dim 16cc+col), row = quad*4 + r (node)
#pragma unroll
        for (int r = 0; r < 4; r++) {
            int onode = t0 + w * 16 + quad * 4 + r;
            if (onode < N) {
                float vv = fmaxf(v[r] + bc, 0.f) * dnv[r];
                out[(long)onode * D + 16 * cc + col] = __float2half(vv);
            }
        }
    }
}

// Variant A (in-run baseline): batch-4 sweep, natural register allocation.
__global__ __launch_bounds__(256) void tile_layer4(const __half* __restrict__ in,
                                                   const int* __restrict__ row_ptr,
                                                   const int* __restrict__ adj,
                                                   const float* __restrict__ dis,
                                                   const float* __restrict__ Wg,
                                                   const float* __restrict__ bias,
                                                   __half* __restrict__ out,
                                                   int N, int scale_out) {
    tile_layer_body<4>(in, row_ptr, adj, dis, Wg, bias, out, N, scale_out);
}

// Variant B (occupancy probe): batch-2 sweep, VGPR capped for 8 waves/SIMD
// (8 blocks/CU with 16384B LDS). Numerically identical to variant A.
__global__ __launch_bounds__(256, 8) void tile_layer2(const __half* __restrict__ in,
                                                      const int* __restrict__ row_ptr,
                                                      const int* __restrict__ adj,
                                                      const float* __restrict__ dis,
                                                      const float* __restrict__ Wg,
                                                      const float* __restrict__ bias,
                                                      __half* __restrict__ out,
                                                      int N, int scale_out) {
    tile_layer_body<2>(in, row_ptr, adj, dis, Wg, bias, out, N, scale_out);
}

// Pool phase 1: grid-chunked over sorted nodes; per-wave run accumulation,
// one atomicAdd per (graph-run, lane) per wave.
__global__ __launch_bounds__(256) void pool_partial(const __half* __restrict__ h,
                                                    const int* __restrict__ batch, int N,
                                                    int chunk, float* __restrict__ pooled) {
    int lane = threadIdx.x & 63;
    int wv = threadIdx.x >> 6;
    int c0 = blockIdx.x * chunk;
    int c1 = min(c0 + chunk, N);
    int g_cur = -1;
    float acc = 0.f;
    for (int n = c0 + wv; n < c1; n += 4) {
        int g = batch[n];
        if (g != g_cur) {
            if (g_cur >= 0) atomicAdd(&pooled[g_cur * D + lane], acc);
            g_cur = g;
            acc = 0.f;
        }
        acc += __half2float(h[n * D + lane]);
    }
    if (g_cur >= 0) atomicAdd(&pooled[g_cur * D + lane], acc);
}

// Pool phase 2: one wave per graph, dot with lin_w.
__global__ void pool_linear(const float* __restrict__ pooled,
                            const float* __restrict__ lin_w,
                            const float* __restrict__ lin_b,
                            float* __restrict__ out, int G) {
    int lane = threadIdx.x & 63;
    int g = blockIdx.x * (blockDim.x >> 6) + (threadIdx.x >> 6);
    if (g >= G) return;
    float t = pooled[g * D + lane] * lin_w[lane];
#pragma unroll
    for (int off = 32; off >= 1; off >>= 1) t += __shfl_down(t, off, 64);
    if (lane == 0) out[g] = t + lin_b[0];
}

extern "C" void kernel_launch(void* const* d_in, const int* in_sizes, int n_in,
                              void* d_out, int out_size, void* d_ws, size_t ws_size,
                              hipStream_t stream) {
    const float* x      = (const float*)d_in[0];
    const int*   edges  = (const int*)d_in[1];
    const int*   batch  = (const int*)d_in[2];
    const float* W1     = (const float*)d_in[3];
    const float* b1     = (const float*)d_in[4];
    const float* W2     = (const float*)d_in[5];
    const float* b2     = (const float*)d_in[6];
    const float* W3     = (const float*)d_in[7];
    const float* b3     = (const float*)d_in[8];
    const float* lin_w  = (const float*)d_in[9];
    const float* lin_b  = (const float*)d_in[10];
    float* out = (float*)d_out;

    const int N = in_sizes[2];        // 100000
    const int E = in_sizes[1] / 2;    // 1600000
    const int G = out_size;           // 64 graphs
    const int nb = (N + 255) >> 8;    // 391 buckets of 256 nodes

    const int* e_src = edges;         // edge_index[0]
    const int* e_dst = edges + E;     // edge_index[1]

    // workspace layout (4B-element offsets, 64-elem aligned)
    auto al = [](long v) { return (v + 63) & ~63L; };
    long o_gcur   = 0;                       // NBMAX ints
    long o_pooled = al(o_gcur + NBMAX);      // G*D floats
    long o_gbase  = al(o_pooled + (long)G * D);
    long o_rowptr = al(o_gbase + nb + 1);
    long o_dis    = al(o_rowptr + N + 1);
    long o_adjs   = al(o_dis + N);
    long o_xh     = al(o_adjs + E);              // N*D halves
    long o_hA     = al(o_xh + (long)N * D / 2);  // aliases bpair (8MB < 25.6MB slot)
    long o_hB     = o_hA + (long)N * D;          // fp32-sized slots used as half buffers

    int*    gcursor = (int*)d_ws + o_gcur;
    float*  pooled  = (float*)d_ws + o_pooled;
    int*    gbase   = (int*)d_ws + o_gbase;
    int*    row_ptr = (int*)d_ws + o_rowptr;
    float*  dis     = (float*)d_ws + o_dis;
    int*    adj     = (int*)d_ws + o_adjs;
    __half* xh      = (__half*)((float*)d_ws + o_xh);
    __half* hA      = (__half*)((float*)d_ws + o_hA);
    __half* hB      = (__half*)((float*)d_ws + o_hB);
    // bpair (nb*BCAP uints = 8 MB) aliases hA slot: dead before layer 2 writes hA.
    unsigned* bpair = (unsigned*)hA;

    // zero gcursor + pooled (contiguous)
    int nz = (int)(o_pooled + (long)G * D);
    zero_ints<<<(nz + 255) / 256, 256, 0, stream>>>((int*)d_ws, nz);

    // CSR build first (produces dis), then pre-scaled fp16 convert of x
    bucket_scatter<<<(E + 4095) / 4096, 256, 0, stream>>>(e_src, e_dst, E, nb, gcursor, bpair);
    scan_buckets<<<1, 512, 0, stream>>>(gcursor, nb, gbase);
    bucket_build<<<nb, 256, 0, stream>>>(bpair, nb, N, gcursor, gbase, row_ptr, dis, adj);

    int n2 = N * D / 2;
    prescale_x<<<(n2 + 255) / 256, 256, 0, stream>>>(x, dis, xh, n2);

    // fused GCN layers: xh -> hB -> hA -> hB
    // layers 1,2 store dis-pre-scaled output; layer 3 stores plain relu for pooling
    // layer 1 = variant A (batch-4 baseline), layers 2,3 = variant B (occupancy probe)
    const int tl_blocks = (N + TILE - 1) / TILE;
    tile_layer4<<<tl_blocks, 256, 0, stream>>>(xh, row_ptr, adj, dis, W1, b1, hB, N, 1);
    tile_layer2<<<tl_blocks, 256, 0, stream>>>(hB, row_ptr, adj, dis, W2, b2, hA, N, 1);
    tile_layer2<<<tl_blocks, 256, 0, stream>>>(hA, row_ptr, adj, dis, W3, b3, hB, N, 0);

    // pool + final linear
    const int pool_blocks = 512;
    const int chunk = (N + pool_blocks - 1) / pool_blocks;
    pool_partial<<<pool_blocks, 256, 0, stream>>>(hB, batch, N, chunk, pooled);
    pool_linear<<<(G + 3) / 4, 256, 0, stream>>>(pooled, lin_w, lin_b, out, G);
}

// Round 6
// 278.211 us; speedup vs baseline: 1.0287x; 1.0287x over previous
//
#include <hip/hip_runtime.h>
#include <hip/hip_fp16.h>

#define D 64
#define NBMAX 512      // max buckets (nodes/256, N<=131072)
#define BCAP 5120      // per-bucket capacity
#define TILE 64        // nodes per block in tile_layer
#define ASTH 72        // LDS bf16 acc row stride in halves (144B: 16B-aligned, 2-way banks)
#define ACAP 448       // per-wave LDS adjacency buffer (entries)
// R4 lessons: (a) occupancy 36->45% with halved MLP = dur unchanged -> NOT
// occupancy-bound (3rd null on concurrency levers). (b) (256,8) bound -> VGPR
// 32 + ~11MB scratch spill (WRITE 12.5->25.9MB) -> never force min-waves here.
// (c) Arithmetic: ~330 G L2-req/s at 42us = chip request-slot ceiling; old
// lane layout (chunk = bytes [c*32, c*32+32)) made each quad's 16B-load span
// two 64B lines half-used -> 4 req/edge, 2x the minimum.
// R5 (rerun; R5 bench was an infra failure, kernel never ran): contiguous-quad
// gather -- lane c loads row bytes [c*16,c*16+16) and [64+c*16, +16): each
// quad instruction = one fully-used 64B line -> 2 req/edge. accb LDS contents
// unchanged (only writer-lane remap); epilogue untouched. Single batch-4
// kernel, natural register allocation.

typedef __attribute__((ext_vector_type(8))) short short8;
typedef __attribute__((ext_vector_type(4))) float float4v;

static __device__ __forceinline__ unsigned short f2bf(float x) {
    unsigned u = __float_as_uint(x);
    u += 0x7FFFu + ((u >> 16) & 1);   // RNE
    return (unsigned short)(u >> 16);
}

__global__ void zero_ints(int* __restrict__ p, int n) {
    int i = blockIdx.x * blockDim.x + threadIdx.x;
    if (i < n) p[i] = 0;
}

// x (fp32) -> xh (fp16), pre-scaled by dis[row]: s = dis[n]*x[n]
__global__ void prescale_x(const float* __restrict__ x, const float* __restrict__ dis,
                           __half* __restrict__ out, int n2) {
    int i = blockIdx.x * blockDim.x + threadIdx.x;
    if (i < n2) {
        int n = i >> 5;                 // 32 half2 per row
        float d = dis[n];
        float2 v = ((const float2*)x)[i];
        ((__half2*)out)[i] = __floats2half2_rn(v.x * d, v.y * d);
    }
}

// Bin edges into buckets of 256 consecutive dst nodes. Entry packed to 4B:
// (src << 8) | (dst & 255)   (src < 2^24).
__global__ __launch_bounds__(256) void bucket_scatter(const int* __restrict__ src,
                                                      const int* __restrict__ dst, int E,
                                                      int nb, int* __restrict__ gcursor,
                                                      unsigned* __restrict__ bpair) {
    __shared__ int lhist[NBMAX];
    __shared__ int lbase[NBMAX];
    int t = threadIdx.x;
    for (int i = t; i < nb; i += 256) lhist[i] = 0;
    __syncthreads();
    int e0 = blockIdx.x * 4096, e1 = min(e0 + 4096, E);
    for (int e = e0 + t; e < e1; e += 256) atomicAdd(&lhist[dst[e] >> 8], 1);
    __syncthreads();
    for (int i = t; i < nb; i += 256) {
        int c = lhist[i];
        lbase[i] = c ? atomicAdd(&gcursor[i], c) : 0;
        lhist[i] = 0;
    }
    __syncthreads();
    for (int e = e0 + t; e < e1; e += 256) {
        int d = dst[e];
        int b = d >> 8;
        int r = lbase[b] + atomicAdd(&lhist[b], 1);
        if (r < BCAP)
            bpair[(long)b * BCAP + r] = ((unsigned)src[e] << 8) | (unsigned)(d & 255);
    }
}

// Exclusive scan of nb (<512) bucket counts -> gbase, total at gbase[nb].
__global__ void scan_buckets(const int* __restrict__ gcursor, int B, int* __restrict__ gbase) {
    __shared__ int s[512];
    int t = threadIdx.x;
    s[t] = (t < B) ? gcursor[t] : 0;
    __syncthreads();
    for (int off = 1; off < 512; off <<= 1) {
        int v = (t >= off) ? s[t - off] : 0;
        __syncthreads();
        s[t] += v;
        __syncthreads();
    }
    if (t < B) gbase[t] = (t == 0) ? 0 : s[t - 1];
    if (t == 0) gbase[B] = s[511];
}

// One block per bucket: local histogram + scan in LDS, emit row_ptr/dis and
// adj entries packed as (src << 6) | (dst & 63)  (tile-local dst, TILE=64).
__global__ __launch_bounds__(256) void bucket_build(const unsigned* __restrict__ bpair,
                                                    int nb, int N,
                                                    const int* __restrict__ gcursor,
                                                    const int* __restrict__ gbase,
                                                    int* __restrict__ row_ptr,
                                                    float* __restrict__ dis,
                                                    int* __restrict__ adj) {
    __shared__ int hist[256];
    __shared__ int cur[256];
    __shared__ int wsum[4];
    int b = blockIdx.x, t = threadIdx.x;
    int cnt = gcursor[b];
    if (cnt > BCAP) cnt = BCAP;
    int ebase = gbase[b];
    const unsigned* bp = bpair + (long)b * BCAP;

    hist[t] = 0;
    __syncthreads();
    for (int i = t; i < cnt; i += 256) atomicAdd(&hist[bp[i] & 255u], 1);
    __syncthreads();
    int val = hist[t];
    int lane = t & 63, wv = t >> 6;
    int v = val;
#pragma unroll
    for (int off = 1; off < 64; off <<= 1) {
        int u = __shfl_up(v, off, 64);
        if (lane >= off) v += u;
    }
    if (lane == 63) wsum[wv] = v;
    __syncthreads();
    int wo = 0;
#pragma unroll
    for (int w = 0; w < 4; w++)
        if (w < wv) wo += wsum[w];
    int excl = wo + v - val;
    int node = (b << 8) + t;
    if (node < N) {
        row_ptr[node] = ebase + excl;
        dis[node] = rsqrtf((float)(val + 1));  // +1 self-loop
    }
    cur[t] = ebase + excl;
    __syncthreads();
    for (int i = t; i < cnt; i += 256) {
        unsigned p = bp[i];
        unsigned dl = p & 255u;
        int pos = atomicAdd(&cur[dl], 1);
        adj[pos] = (int)((p >> 8) << 6) | (int)(dl & 63u);
    }
    if (b == 0 && t == 0) row_ptr[N] = gbase[nb];
}

// Tile GCN layer on pre-scaled storage s[n] = dis[n]*h[n]:
//   y[n] = dis[n] * ( sum_a s[a] + s[n] );  o = relu(y @ W + b); store (*dis if scale_out)
// Block = 64-node tile, 4 waves x 16 rows. Lane = (row = lane>>2, c = lane&3).
// CONTIGUOUS-QUAD layout: lane c owns row bytes [c*16,c*16+16) and
// [64+c*16,+16) (channels [8c,8c+8) and [32+8c,+8)). Each quad's load
// instruction covers ONE fully-used 64B line -> 2 L2 requests/edge (the
// previous interleaved layout cost 4 half-used -- R4 showed we sit at the L2
// request-slot ceiling). Per-lane fp32 register accumulation, no LDS atomics,
// no divergence. Epilogue: *dis, bf16 pack, two 16B LDS writes, wave-local
// waitcnt, per-wave MFMA with per-quadrant B-frags.
template <int NB>
static __device__ __forceinline__ void tile_layer_body(const __half* __restrict__ in,
                                                       const int* __restrict__ row_ptr,
                                                       const int* __restrict__ adj,
                                                       const float* __restrict__ dis,
                                                       const float* __restrict__ Wg,
                                                       const float* __restrict__ bias,
                                                       __half* __restrict__ out,
                                                       int N, int scale_out) {
    __shared__ __align__(16) unsigned short accb[TILE * ASTH];  // 9216 B bf16 acc
    __shared__ int adjbuf[4][ACAP];                             // 7168 B wave-private

    int t = threadIdx.x;
    int lane = t & 63;
    int w = t >> 6;
    int row = lane >> 2;                    // wave-local row 0..15
    int c = lane & 3;                       // quad slot
    int col = lane & 15, quad = lane >> 4;  // epilogue MFMA coords

    int t0 = blockIdx.x * TILE;
    int wbase = t0 + w * 16;
    int node = wbase + row;

    // per-lane CSR range (empty for tail rows)
    int e0r = 0, e1r = 0;
    if (node < N) { e0r = row_ptr[node]; e1r = row_ptr[node + 1]; }

    const char* inb = (const char*)in;
    int* adjw = adjbuf[w];
    unsigned c16 = (unsigned)c * 16u;       // byte offset within each 64B half-row

    float a[16];                            // a[0..7]=ch[8c..8c+8), a[8..15]=ch[32+8c..)
#pragma unroll
    for (int j = 0; j < 16; j++) a[j] = 0.f;

#define ADD16(xa, ya)                                                   \
    {                                                                   \
        const __half2* h0 = (const __half2*)&(xa);                      \
        const __half2* h1 = (const __half2*)&(ya);                      \
        _Pragma("unroll")                                               \
        for (int j = 0; j < 4; j++) {                                   \
            float2 f = __half22float2(h0[j]);                           \
            a[2 * j] += f.x; a[2 * j + 1] += f.y;                       \
        }                                                               \
        _Pragma("unroll")                                               \
        for (int j = 0; j < 4; j++) {                                   \
            float2 f = __half22float2(h1[j]);                           \
            a[8 + 2 * j] += f.x; a[8 + 2 * j + 1] += f.y;               \
        }                                                               \
    }

    if (node < N) {
        unsigned rb = (unsigned)node * 128u + c16;
        int4 xa = *(const int4*)(inb + rb);
        int4 xb = *(const int4*)(inb + rb + 64);
        ADD16(xa, xb)
    }

    // ---- edge sweep: wave's contiguous CSR range, staged in ACAP chunks ----
    int wn0 = min(wbase, N);
    int wn1 = min(wbase + 16, N);
    int eb_w = row_ptr[wn0];
    int ee_w = row_ptr[wn1];

    for (int base = eb_w; base < ee_w; base += ACAP) {
        int clen = min(ACAP, ee_w - base);
        // cooperative wave-copy of adj slice (coalesced dwords); wave-private.
        for (int i = lane; i < clen; i += 64) adjw[i] = adj[base + i];
        __builtin_amdgcn_s_waitcnt(0);   // drain lds writes + vm before reads

        int ls = max(e0r - base, 0);
        int le = min(e1r - base, clen);
        int cnt = max(le - ls, 0);
        int kmax = cnt;
#pragma unroll
        for (int off = 32; off >= 1; off >>= 1) {
            int o = __shfl_xor(kmax, off, 64);
            kmax = max(kmax, o);
        }
        int sidx = min(ls, clen - 1);    // safe clamped index for short lanes

        for (int k = 0; k < kmax; k += NB) {
            bool ok[NB];
            unsigned ro[NB];
            int4 xa[NB], xb[NB];
#pragma unroll
            for (int u = 0; u < NB; u++) {
                int idx = ls + k + u;
                ok[u] = idx < le;
                int pk = adjw[ok[u] ? idx : sidx];
                ro[u] = (unsigned)(pk >> 6) * 128u + c16;
            }
#pragma unroll
            for (int u = 0; u < NB; u++) {
                xa[u] = *(const int4*)(inb + ro[u]);        // quad: one 64B line
                xb[u] = *(const int4*)(inb + ro[u] + 64);   // quad: one 64B line
            }
#pragma unroll
            for (int u = 0; u < NB; u++)
                if (ok[u]) ADD16(xa[u], xb[u])
        }
    }
#undef ADD16

    // scale by dis(own row), convert to bf16, two 16B LDS writes
    float dA = (node < N) ? dis[node] : 0.f;
    unsigned short* ab = &accb[(w * 16 + row) * ASTH];
    unsigned pk[8];
#pragma unroll
    for (int j = 0; j < 8; j++)
        pk[j] = (unsigned)f2bf(a[2 * j] * dA) | ((unsigned)f2bf(a[2 * j + 1] * dA) << 16);
    *(int4*)(ab + 8 * c) = make_int4((int)pk[0], (int)pk[1], (int)pk[2], (int)pk[3]);
    *(int4*)(ab + 32 + 8 * c) = make_int4((int)pk[4], (int)pk[5], (int)pk[6], (int)pk[7]);
    __builtin_amdgcn_s_waitcnt(0);   // wave-local: acc rows read only by this wave

    // ---- MFMA epilogue: per wave, rows w*16 .. w*16+15 ----
    // A frags: row m = col, k = 32s + quad*8 + j (bf16 direct from LDS)
    const unsigned short* arp = &accb[(w * 16 + col) * ASTH + quad * 8];
    short8 Af0 = *(const short8*)arp;
    short8 Af1 = *(const short8*)(arp + 32);

    float dnv[4];
#pragma unroll
    for (int r = 0; r < 4; r++) {
        int onode = t0 + w * 16 + quad * 4 + r;
        dnv[r] = (onode < N) ? (scale_out ? dis[onode] : 1.f) : 0.f;
    }

    // B frags per output quadrant cc: B[k=32s+quad*8+j][d=16cc+col]
#pragma unroll
    for (int cc = 0; cc < 4; cc++) {
        short8 B0, B1;
#pragma unroll
        for (int j = 0; j < 8; j++) {
            B0[j] = (short)f2bf(Wg[(quad * 8 + j) * D + 16 * cc + col]);
            B1[j] = (short)f2bf(Wg[(32 + quad * 8 + j) * D + 16 * cc + col]);
        }
        float4v z = {0.f, 0.f, 0.f, 0.f};
        float4v v = __builtin_amdgcn_mfma_f32_16x16x32_bf16(Af0, B0, z, 0, 0, 0);
        v = __builtin_amdgcn_mfma_f32_16x16x32_bf16(Af1, B1, v, 0, 0, 0);
        float bc = bias[16 * cc + col];
        // C layout: col = lane&15 (dim 16cc+col), row = quad*4 + r (node)
#pragma unroll
        for (int r = 0; r < 4; r++) {
            int onode = t0 + w * 16 + quad * 4 + r;
            if (onode < N) {
                float vv = fmaxf(v[r] + bc, 0.f) * dnv[r];
                out[(long)onode * D + 16 * cc + col] = __float2half(vv);
            }
        }
    }
}

// Single variant: batch-4 sweep, natural register allocation (R4: forcing
// min-waves spilled; occupancy is not the lever).
__global__ __launch_bounds__(256) void tile_layer(const __half* __restrict__ in,
                                                  const int* __restrict__ row_ptr,
                                                  const int* __restrict__ adj,
                                                  const float* __restrict__ dis,
                                                  const float* __restrict__ Wg,
                                                  const float* __restrict__ bias,
                                                  __half* __restrict__ out,
                                                  int N, int scale_out) {
    tile_layer_body<4>(in, row_ptr, adj, dis, Wg, bias, out, N, scale_out);
}

// Pool phase 1: grid-chunked over sorted nodes; per-wave run accumulation,
// one atomicAdd per (graph-run, lane) per wave.
__global__ __launch_bounds__(256) void pool_partial(const __half* __restrict__ h,
                                                    const int* __restrict__ batch, int N,
                                                    int chunk, float* __restrict__ pooled) {
    int lane = threadIdx.x & 63;
    int wv = threadIdx.x >> 6;
    int c0 = blockIdx.x * chunk;
    int c1 = min(c0 + chunk, N);
    int g_cur = -1;
    float acc = 0.f;
    for (int n = c0 + wv; n < c1; n += 4) {
        int g = batch[n];
        if (g != g_cur) {
            if (g_cur >= 0) atomicAdd(&pooled[g_cur * D + lane], acc);
            g_cur = g;
            acc = 0.f;
        }
        acc += __half2float(h[n * D + lane]);
    }
    if (g_cur >= 0) atomicAdd(&pooled[g_cur * D + lane], acc);
}

// Pool phase 2: one wave per graph, dot with lin_w.
__global__ void pool_linear(const float* __restrict__ pooled,
                            const float* __restrict__ lin_w,
                            const float* __restrict__ lin_b,
                            float* __restrict__ out, int G) {
    int lane = threadIdx.x & 63;
    int g = blockIdx.x * (blockDim.x >> 6) + (threadIdx.x >> 6);
    if (g >= G) return;
    float t = pooled[g * D + lane] * lin_w[lane];
#pragma unroll
    for (int off = 32; off >= 1; off >>= 1) t += __shfl_down(t, off, 64);
    if (lane == 0) out[g] = t + lin_b[0];
}

extern "C" void kernel_launch(void* const* d_in, const int* in_sizes, int n_in,
                              void* d_out, int out_size, void* d_ws, size_t ws_size,
                              hipStream_t stream) {
    const float* x      = (const float*)d_in[0];
    const int*   edges  = (const int*)d_in[1];
    const int*   batch  = (const int*)d_in[2];
    const float* W1     = (const float*)d_in[3];
    const float* b1     = (const float*)d_in[4];
    const float* W2     = (const float*)d_in[5];
    const float* b2     = (const float*)d_in[6];
    const float* W3     = (const float*)d_in[7];
    const float* b3     = (const float*)d_in[8];
    const float* lin_w  = (const float*)d_in[9];
    const float* lin_b  = (const float*)d_in[10];
    float* out = (float*)d_out;

    const int N = in_sizes[2];        // 100000
    const int E = in_sizes[1] / 2;    // 1600000
    const int G = out_size;           // 64 graphs
    const int nb = (N + 255) >> 8;    // 391 buckets of 256 nodes

    const int* e_src = edges;         // edge_index[0]
    const int* e_dst = edges + E;     // edge_index[1]

    // workspace layout (4B-element offsets, 64-elem aligned)
    auto al = [](long v) { return (v + 63) & ~63L; };
    long o_gcur   = 0;                       // NBMAX ints
    long o_pooled = al(o_gcur + NBMAX);      // G*D floats
    long o_gbase  = al(o_pooled + (long)G * D);
    long o_rowptr = al(o_gbase + nb + 1);
    long o_dis    = al(o_rowptr + N + 1);
    long o_adjs   = al(o_dis + N);
    long o_xh     = al(o_adjs + E);              // N*D halves
    long o_hA     = al(o_xh + (long)N * D / 2);  // aliases bpair (8MB < 25.6MB slot)
    long o_hB     = o_hA + (long)N * D;          // fp32-sized slots used as half buffers

    int*    gcursor = (int*)d_ws + o_gcur;
    float*  pooled  = (float*)d_ws + o_pooled;
    int*    gbase   = (int*)d_ws + o_gbase;
    int*    row_ptr = (int*)d_ws + o_rowptr;
    float*  dis     = (float*)d_ws + o_dis;
    int*    adj     = (int*)d_ws + o_adjs;
    __half* xh      = (__half*)((float*)d_ws + o_xh);
    __half* hA      = (__half*)((float*)d_ws + o_hA);
    __half* hB      = (__half*)((float*)d_ws + o_hB);
    // bpair (nb*BCAP uints = 8 MB) aliases hA slot: dead before layer 2 writes hA.
    unsigned* bpair = (unsigned*)hA;

    // zero gcursor + pooled (contiguous)
    int nz = (int)(o_pooled + (long)G * D);
    zero_ints<<<(nz + 255) / 256, 256, 0, stream>>>((int*)d_ws, nz);

    // CSR build first (produces dis), then pre-scaled fp16 convert of x
    bucket_scatter<<<(E + 4095) / 4096, 256, 0, stream>>>(e_src, e_dst, E, nb, gcursor, bpair);
    scan_buckets<<<1, 512, 0, stream>>>(gcursor, nb, gbase);
    bucket_build<<<nb, 256, 0, stream>>>(bpair, nb, N, gcursor, gbase, row_ptr, dis, adj);

    int n2 = N * D / 2;
    prescale_x<<<(n2 + 255) / 256, 256, 0, stream>>>(x, dis, xh, n2);

    // fused GCN layers: xh -> hB -> hA -> hB
    // layers 1,2 store dis-pre-scaled output; layer 3 stores plain relu for pooling
    const int tl_blocks = (N + TILE - 1) / TILE;
    tile_layer<<<tl_blocks, 256, 0, stream>>>(xh, row_ptr, adj, dis, W1, b1, hB, N, 1);
    tile_layer<<<tl_blocks, 256, 0, stream>>>(hB, row_ptr, adj, dis, W2, b2, hA, N, 1);
    tile_layer<<<tl_blocks, 256, 0, stream>>>(hA, row_ptr, adj, dis, W3, b3, hB, N, 0);

    // pool + final linear
    const int pool_blocks = 512;
    const int chunk = (N + pool_blocks - 1) / pool_blocks;
    pool_partial<<<pool_blocks, 256, 0, stream>>>(hB, batch, N, chunk, pooled);
    pool_linear<<<(G + 3) / 4, 256, 0, stream>>>(pooled, lin_w, lin_b, out, G);
}